// Round 1
// baseline (145.154 us; speedup 1.0000x reference)
//
#include <hip/hip_runtime.h>
#include <hip/hip_bf16.h>

#define BATCH 8
#define SEQ   2048
#define DIM   512
#define HD    64
#define NEGV  (-1e30f)

typedef float f32x4  __attribute__((ext_vector_type(4)));
typedef short bf16x8 __attribute__((ext_vector_type(8)));

__device__ __forceinline__ short f2bf(float f) {
  unsigned u = __builtin_bit_cast(unsigned, f);
  u += 0x7fffu + ((u >> 16) & 1u);
  return (short)(u >> 16);
}

// ---------------- Kernel 1: QKV projection (fp32 vector, bf16 out) ----------
// Block: 256 threads handles 32 rows x 192 cols. x tile staged in LDS.
__global__ __launch_bounds__(256) void qkv_kernel(
    const float* __restrict__ x,
    const float* __restrict__ Wq, const float* __restrict__ bq,
    const float* __restrict__ Wk, const float* __restrict__ bk,
    const float* __restrict__ Wv, const float* __restrict__ bv,
    short* __restrict__ Qb, short* __restrict__ Kb, short* __restrict__ Vt)
{
  __shared__ float xs[32][32];
  const int tid = threadIdx.x;
  const int col = tid & 63;   // h index
  const int rg  = tid >> 6;   // row group 0..3 (8 rows each)
  const long r0 = (long)blockIdx.x * 32;

  float aq[8], ak[8], av[8];
  #pragma unroll
  for (int i = 0; i < 8; ++i) { aq[i] = 0.f; ak[i] = 0.f; av[i] = 0.f; }

  const int sr = tid >> 3;          // 0..31
  const int sc = (tid & 7) << 2;    // 0..28

  for (int k0 = 0; k0 < DIM; k0 += 32) {
    __syncthreads();
    *(float4*)&xs[sr][sc] = *(const float4*)&x[(r0 + sr) * DIM + k0 + sc];
    __syncthreads();
    #pragma unroll 4
    for (int kk = 0; kk < 32; ++kk) {
      const int k = k0 + kk;
      const float wq = Wq[k * HD + col];
      const float wk = Wk[k * HD + col];
      const float wv = Wv[k * HD + col];
      #pragma unroll
      for (int rr = 0; rr < 8; ++rr) {
        const float xv = xs[rg * 8 + rr][kk];
        aq[rr] = fmaf(xv, wq, aq[rr]);
        ak[rr] = fmaf(xv, wk, ak[rr]);
        av[rr] = fmaf(xv, wv, av[rr]);
      }
    }
  }

  const float bqv = bq[col], bkv = bk[col], bvv = bv[col];
  #pragma unroll
  for (int rr = 0; rr < 8; ++rr) {
    const long row = r0 + rg * 8 + rr;
    const int b = (int)(row >> 11);
    const int t = (int)(row & 2047);
    Qb[row * HD + col] = f2bf(aq[rr] + bqv);
    Kb[row * HD + col] = f2bf(ak[rr] + bkv);
    Vt[((long)b * HD + col) * SEQ + t] = f2bf(av[rr] + bvv);
  }
}

// ---------------- Kernel 2: flash attention, bf16 MFMA 16x16x32 -------------
// Grid: (T/64, B). Block: 4 waves; wave w owns 16 query rows.
// MFMA 16x16x32 layouts (m89-verified):
//   A[m][k]: m = lane&15, k = (lane>>4)*8 + j
//   B[k][n]: n = lane&15, k = (lane>>4)*8 + j
//   D[m][n]: n = lane&15, m = (lane>>4)*4 + reg
__global__ __launch_bounds__(256) void attn_kernel(
    const short* __restrict__ Qb, const short* __restrict__ Kb,
    const short* __restrict__ Vt, const unsigned char* __restrict__ pmask,
    float* __restrict__ out)
{
  __shared__ short kt_lds[64 * 64];   // [key][h], XOR-swizzled rows (128B)
  __shared__ short vt_lds[64 * 64];   // [h][key], XOR-swizzled rows (128B)
  __shared__ float mask_lds[64];
  __shared__ short p_lds[4][16 * 72]; // per-wave P, padded stride 72 (144B)

  const int b    = blockIdx.y;
  const int qt   = blockIdx.x;
  const int q0   = qt * 64;
  const int tid  = threadIdx.x;
  const int w    = tid >> 6;
  const int lane = tid & 63;
  const int lc   = lane & 15;
  const int lg   = lane >> 4;

  // Q fragments (A-operand): row = lane&15 -> query q0+16w+lc
  const long qrow = (long)b * SEQ + q0 + w * 16 + lc;
  bf16x8 qf[2];
  #pragma unroll
  for (int s = 0; s < 2; ++s)
    qf[s] = *(const bf16x8*)&Qb[qrow * HD + s * 32 + lg * 8];

  f32x4 o[4];
  #pragma unroll
  for (int n = 0; n < 4; ++n)
    #pragma unroll
    for (int i = 0; i < 4; ++i) o[n][i] = 0.f;
  float m[4], l[4];
  #pragma unroll
  for (int r = 0; r < 4; ++r) { m[r] = NEGV; l[r] = 0.f; }

  for (int kt = 0; kt <= qt; ++kt) {
    __syncthreads();
    // stage K tile [64 keys][64 h] and V^T tile [64 h][64 keys]
    #pragma unroll
    for (int i = 0; i < 2; ++i) {
      const int idx = tid + i * 256;          // 0..511
      const int row = idx >> 3;               // 0..63
      const int cb  = (idx & 7) << 4;         // col byte 0..112
      const int swz = cb ^ ((row & 7) << 4);
      *(bf16x8*)((char*)kt_lds + row * 128 + swz) =
          *(const bf16x8*)&Kb[((long)b * SEQ + kt * 64 + row) * HD + (idx & 7) * 8];
      *(bf16x8*)((char*)vt_lds + row * 128 + swz) =
          *(const bf16x8*)&Vt[((long)b * HD + row) * SEQ + kt * 64 + (idx & 7) * 8];
    }
    if (tid < 64)
      mask_lds[tid] = pmask[(long)b * SEQ + kt * 64 + tid] ? NEGV : 0.f;
    __syncthreads();

    // S = Q K^T  (16 queries x 64 keys per wave)
    f32x4 sf[4];
    #pragma unroll
    for (int n = 0; n < 4; ++n) {
      f32x4 acc;
      #pragma unroll
      for (int i = 0; i < 4; ++i) acc[i] = 0.f;
      const int row = n * 16 + lc;            // key within tile
      #pragma unroll
      for (int s = 0; s < 2; ++s) {
        bf16x8 kf = *(const bf16x8*)((const char*)kt_lds + row * 128 +
                        ((s * 64 + lg * 16) ^ ((row & 7) << 4)));
        acc = __builtin_amdgcn_mfma_f32_16x16x32_bf16(qf[s], kf, acc, 0, 0, 0);
      }
      sf[n] = acc;
    }

    // scale + padding + causal mask
    const bool diag = (kt == qt);
    #pragma unroll
    for (int n = 0; n < 4; ++n) {
      const int key = kt * 64 + n * 16 + lc;
      const float madd = mask_lds[n * 16 + lc];
      #pragma unroll
      for (int r = 0; r < 4; ++r) {
        float v = sf[n][r] * 0.125f + madd;
        if (diag) {
          const int q = q0 + w * 16 + lg * 4 + r;
          if (key > q) v = NEGV;
        }
        sf[n][r] = v;
      }
    }

    // online softmax: queries live in (lg, r); keys in (n, lc)
    float tm[4];
    #pragma unroll
    for (int r = 0; r < 4; ++r)
      tm[r] = fmaxf(fmaxf(sf[0][r], sf[1][r]), fmaxf(sf[2][r], sf[3][r]));
    #pragma unroll
    for (int r = 0; r < 4; ++r) {
      tm[r] = fmaxf(tm[r], __shfl_xor(tm[r], 1));
      tm[r] = fmaxf(tm[r], __shfl_xor(tm[r], 2));
      tm[r] = fmaxf(tm[r], __shfl_xor(tm[r], 4));
      tm[r] = fmaxf(tm[r], __shfl_xor(tm[r], 8));
    }
    float corr[4];
    #pragma unroll
    for (int r = 0; r < 4; ++r) {
      const float mn = fmaxf(m[r], tm[r]);
      corr[r] = __expf(m[r] - mn);
      m[r] = mn;
    }
    float rs[4];
    #pragma unroll
    for (int r = 0; r < 4; ++r) rs[r] = 0.f;
    #pragma unroll
    for (int n = 0; n < 4; ++n)
      #pragma unroll
      for (int r = 0; r < 4; ++r) {
        const float p = __expf(sf[n][r] - m[r]);
        sf[n][r] = p;
        rs[r] += p;
      }
    #pragma unroll
    for (int r = 0; r < 4; ++r) {
      rs[r] += __shfl_xor(rs[r], 1);
      rs[r] += __shfl_xor(rs[r], 2);
      rs[r] += __shfl_xor(rs[r], 4);
      rs[r] += __shfl_xor(rs[r], 8);
      l[r] = l[r] * corr[r] + rs[r];
    }

    // P -> LDS (bf16), per-wave region
    #pragma unroll
    for (int n = 0; n < 4; ++n)
      #pragma unroll
      for (int r = 0; r < 4; ++r)
        p_lds[w][(lg * 4 + r) * 72 + n * 16 + lc] = f2bf(sf[n][r]);

    // rescale O
    #pragma unroll
    for (int n = 0; n < 4; ++n)
      #pragma unroll
      for (int r = 0; r < 4; ++r)
        o[n][r] *= corr[r];

    // O += P V
    #pragma unroll
    for (int s = 0; s < 2; ++s) {
      const bf16x8 pa = *(const bf16x8*)&p_lds[w][lc * 72 + s * 32 + lg * 8];
      #pragma unroll
      for (int n = 0; n < 4; ++n) {
        const int h = n * 16 + lc;
        const bf16x8 vf = *(const bf16x8*)((const char*)vt_lds + h * 128 +
                              ((s * 64 + lg * 16) ^ ((h & 7) << 4)));
        o[n] = __builtin_amdgcn_mfma_f32_16x16x32_bf16(pa, vf, o[n], 0, 0, 0);
      }
    }
  }

  // epilogue: O / l
  #pragma unroll
  for (int r = 0; r < 4; ++r) {
    const float inv = 1.f / l[r];
    const long row = (long)b * SEQ + q0 + w * 16 + lg * 4 + r;
    #pragma unroll
    for (int n = 0; n < 4; ++n)
      out[row * HD + n * 16 + lc] = o[n][r] * inv;
  }
}

extern "C" void kernel_launch(void* const* d_in, const int* in_sizes, int n_in,
                              void* d_out, int out_size, void* d_ws, size_t ws_size,
                              hipStream_t stream) {
  const float* x  = (const float*)d_in[0];
  const unsigned char* pmask = (const unsigned char*)d_in[1];
  const float* Wq = (const float*)d_in[2];
  const float* bq = (const float*)d_in[3];
  const float* Wk = (const float*)d_in[4];
  const float* bk = (const float*)d_in[5];
  const float* Wv = (const float*)d_in[6];
  const float* bv = (const float*)d_in[7];
  float* out = (float*)d_out;

  short* Qb = (short*)d_ws;                       // [B*T*H] bf16
  short* Kb = Qb + (size_t)BATCH * SEQ * HD;      // [B*T*H] bf16
  short* Vt = Kb + (size_t)BATCH * SEQ * HD;      // [B*H*T] bf16 (transposed)

  qkv_kernel<<<dim3((BATCH * SEQ) / 32), dim3(256), 0, stream>>>(
      x, Wq, bq, Wk, bk, Wv, bv, Qb, Kb, Vt);
  attn_kernel<<<dim3(SEQ / 64, BATCH), dim3(256), 0, stream>>>(
      Qb, Kb, Vt, pmask, out);
}

// Round 2
// 89.798 us; speedup vs baseline: 1.6164x; 1.6164x over previous
//
#include <hip/hip_runtime.h>
#include <hip/hip_bf16.h>

#define BATCH 8
#define SEQ   2048
#define DIM   512
#define HD    64
#define NEGV  (-1e30f)

typedef float f32x4  __attribute__((ext_vector_type(4)));
typedef short bf16x8 __attribute__((ext_vector_type(8)));
typedef short bf16x4 __attribute__((ext_vector_type(4)));

__device__ __forceinline__ short f2bf(float f) {
  unsigned u = __builtin_bit_cast(unsigned, f);
  u += 0x7fffu + ((u >> 16) & 1u);
  return (short)(u >> 16);
}

// ---------------- Kernel 0: W transpose+convert -> Wt bf16 [192][512] -------
__global__ __launch_bounds__(256) void prep_w(
    const float* __restrict__ Wq, const float* __restrict__ Wk,
    const float* __restrict__ Wv, short* __restrict__ Wt)
{
  __shared__ float lds[64][65];
  const int mat = blockIdx.x % 3;
  const int kb  = blockIdx.x / 3;          // k-block of 64
  const float* W = mat == 0 ? Wq : (mat == 1 ? Wk : Wv);
  const int tid = threadIdx.x;

  #pragma unroll
  for (int i = 0; i < 4; ++i) {
    const int kr = i * 16 + (tid >> 4);
    const int col = (tid & 15) * 4;
    *(float4*)&lds[kr][col] = *(const float4*)&W[(kb * 64 + kr) * HD + col];
  }
  __syncthreads();
  #pragma unroll
  for (int i = 0; i < 2; ++i) {
    const int c = tid + i * 256;           // 0..511
    const int n = c >> 3, seg = c & 7;
    bf16x8 o;
    #pragma unroll
    for (int j = 0; j < 8; ++j) o[j] = f2bf(lds[seg * 8 + j][n]);
    *(bf16x8*)&Wt[(mat * 64 + n) * DIM + kb * 64 + seg * 8] = o;
  }
}

// ---------------- Kernel 1: QKV projection via MFMA --------------------------
// Grid 256 blocks (M-tile 64), 4 waves. Wave w: cols w*48..w*48+47, rows 0..63.
// Per K-step (BK=32): 12 MFMA vs 7 ds_read_b128 per wave.
__global__ __launch_bounds__(256) void qkv_gemm(
    const float* __restrict__ x, const short* __restrict__ Wt,
    const float* __restrict__ bq, const float* __restrict__ bk,
    const float* __restrict__ bv,
    short* __restrict__ Qb, short* __restrict__ Kb, short* __restrict__ Vt)
{
  __shared__ short xs[64 * 40];   // [row][k], stride 40 bf16 (80B)
  __shared__ short ws[192 * 40];  // [col][k], stride 40 bf16

  const int tid  = threadIdx.x;
  const int lane = tid & 63;
  const int w    = tid >> 6;
  const int lc   = lane & 15;
  const int lg   = lane >> 4;
  const long r0  = (long)blockIdx.x * 64;

  f32x4 acc[4][3];
  #pragma unroll
  for (int m = 0; m < 4; ++m)
    #pragma unroll
    for (int n = 0; n < 3; ++n)
      #pragma unroll
      for (int i = 0; i < 4; ++i) acc[m][n][i] = 0.f;

  float4 xv[2];
  bf16x8 wv[3];

  auto load_tile = [&](int k0) {
    #pragma unroll
    for (int i = 0; i < 2; ++i) {
      const int c = tid + i * 256, row = c >> 3, seg = c & 7;
      xv[i] = *(const float4*)&x[(r0 + row) * DIM + k0 + seg * 4];
    }
    #pragma unroll
    for (int i = 0; i < 3; ++i) {
      const int c = tid + i * 256, row = c >> 2, seg = c & 3;
      wv[i] = *(const bf16x8*)&Wt[row * DIM + k0 + seg * 8];
    }
  };
  auto write_tile = [&]() {
    #pragma unroll
    for (int i = 0; i < 2; ++i) {
      const int c = tid + i * 256, row = c >> 3, seg = c & 7;
      bf16x4 t;
      t[0] = f2bf(xv[i].x); t[1] = f2bf(xv[i].y);
      t[2] = f2bf(xv[i].z); t[3] = f2bf(xv[i].w);
      *(bf16x4*)&xs[row * 40 + seg * 4] = t;
    }
    #pragma unroll
    for (int i = 0; i < 3; ++i) {
      const int c = tid + i * 256, row = c >> 2, seg = c & 3;
      *(bf16x8*)&ws[row * 40 + seg * 8] = wv[i];
    }
  };

  load_tile(0);
  write_tile();
  __syncthreads();

  for (int kt = 0; kt < 16; ++kt) {
    if (kt < 15) load_tile((kt + 1) * 32);

    bf16x8 a[4], b[3];
    #pragma unroll
    for (int m = 0; m < 4; ++m)
      a[m] = *(const bf16x8*)&xs[(m * 16 + lc) * 40 + lg * 8];
    #pragma unroll
    for (int n = 0; n < 3; ++n)
      b[n] = *(const bf16x8*)&ws[(w * 48 + n * 16 + lc) * 40 + lg * 8];
    #pragma unroll
    for (int m = 0; m < 4; ++m)
      #pragma unroll
      for (int n = 0; n < 3; ++n)
        acc[m][n] = __builtin_amdgcn_mfma_f32_16x16x32_bf16(a[m], b[n], acc[m][n], 0, 0, 0);

    __syncthreads();
    if (kt < 15) {
      write_tile();
      __syncthreads();
    }
  }

  // epilogue: +bias, bf16, route to Q/K/Vt
  #pragma unroll
  for (int n = 0; n < 3; ++n) {
    const int col = w * 48 + n * 16 + lc;
    const int mat = col >> 6;            // wave-uniform (16-col block)
    const int h   = col & 63;
    const float bias = (mat == 0 ? bq : (mat == 1 ? bk : bv))[h];
    #pragma unroll
    for (int m = 0; m < 4; ++m)
      #pragma unroll
      for (int r = 0; r < 4; ++r) {
        const long row = r0 + m * 16 + lg * 4 + r;
        const short o = f2bf(acc[m][n][r] + bias);
        if (mat == 0)      Qb[row * HD + h] = o;
        else if (mat == 1) Kb[row * HD + h] = o;
        else {
          const int bb = (int)(row >> 11), t = (int)(row & 2047);
          Vt[((long)bb * HD + h) * SEQ + t] = o;
        }
      }
  }
}

// ---------------- Kernel 2: flash attention, bf16 MFMA 16x16x32 -------------
__global__ __launch_bounds__(256) void attn_kernel(
    const short* __restrict__ Qb, const short* __restrict__ Kb,
    const short* __restrict__ Vt, const unsigned char* __restrict__ pmask,
    float* __restrict__ out)
{
  __shared__ short kt_lds[64 * 64];   // [key][h], XOR-swizzled rows (128B)
  __shared__ short vt_lds[64 * 64];   // [h][key], XOR-swizzled rows (128B)
  __shared__ float mask_lds[64];
  __shared__ short p_lds[4][16 * 72]; // per-wave P, padded stride 72

  const int b    = blockIdx.y;
  const int qt   = blockIdx.x;
  const int q0   = qt * 64;
  const int tid  = threadIdx.x;
  const int w    = tid >> 6;
  const int lane = tid & 63;
  const int lc   = lane & 15;
  const int lg   = lane >> 4;

  const long qrow = (long)b * SEQ + q0 + w * 16 + lc;
  bf16x8 qf[2];
  #pragma unroll
  for (int s = 0; s < 2; ++s)
    qf[s] = *(const bf16x8*)&Qb[qrow * HD + s * 32 + lg * 8];

  f32x4 o[4];
  #pragma unroll
  for (int n = 0; n < 4; ++n)
    #pragma unroll
    for (int i = 0; i < 4; ++i) o[n][i] = 0.f;
  float m[4], l[4];
  #pragma unroll
  for (int r = 0; r < 4; ++r) { m[r] = NEGV; l[r] = 0.f; }

  for (int kt = 0; kt <= qt; ++kt) {
    __syncthreads();
    #pragma unroll
    for (int i = 0; i < 2; ++i) {
      const int idx = tid + i * 256;
      const int row = idx >> 3;
      const int cb  = (idx & 7) << 4;
      const int swz = cb ^ ((row & 7) << 4);
      *(bf16x8*)((char*)kt_lds + row * 128 + swz) =
          *(const bf16x8*)&Kb[((long)b * SEQ + kt * 64 + row) * HD + (idx & 7) * 8];
      *(bf16x8*)((char*)vt_lds + row * 128 + swz) =
          *(const bf16x8*)&Vt[((long)b * HD + row) * SEQ + kt * 64 + (idx & 7) * 8];
    }
    if (tid < 64)
      mask_lds[tid] = pmask[(long)b * SEQ + kt * 64 + tid] ? NEGV : 0.f;
    __syncthreads();

    f32x4 sf[4];
    #pragma unroll
    for (int n = 0; n < 4; ++n) {
      f32x4 acc;
      #pragma unroll
      for (int i = 0; i < 4; ++i) acc[i] = 0.f;
      const int row = n * 16 + lc;
      #pragma unroll
      for (int s = 0; s < 2; ++s) {
        bf16x8 kf = *(const bf16x8*)((const char*)kt_lds + row * 128 +
                        ((s * 64 + lg * 16) ^ ((row & 7) << 4)));
        acc = __builtin_amdgcn_mfma_f32_16x16x32_bf16(qf[s], kf, acc, 0, 0, 0);
      }
      sf[n] = acc;
    }

    const bool diag = (kt == qt);
    #pragma unroll
    for (int n = 0; n < 4; ++n) {
      const int key = kt * 64 + n * 16 + lc;
      const float madd = mask_lds[n * 16 + lc];
      #pragma unroll
      for (int r = 0; r < 4; ++r) {
        float v = sf[n][r] * 0.125f + madd;
        if (diag) {
          const int q = q0 + w * 16 + lg * 4 + r;
          if (key > q) v = NEGV;
        }
        sf[n][r] = v;
      }
    }

    float tm[4];
    #pragma unroll
    for (int r = 0; r < 4; ++r)
      tm[r] = fmaxf(fmaxf(sf[0][r], sf[1][r]), fmaxf(sf[2][r], sf[3][r]));
    #pragma unroll
    for (int r = 0; r < 4; ++r) {
      tm[r] = fmaxf(tm[r], __shfl_xor(tm[r], 1));
      tm[r] = fmaxf(tm[r], __shfl_xor(tm[r], 2));
      tm[r] = fmaxf(tm[r], __shfl_xor(tm[r], 4));
      tm[r] = fmaxf(tm[r], __shfl_xor(tm[r], 8));
    }
    float corr[4];
    #pragma unroll
    for (int r = 0; r < 4; ++r) {
      const float mn = fmaxf(m[r], tm[r]);
      corr[r] = __expf(m[r] - mn);
      m[r] = mn;
    }
    float rs[4];
    #pragma unroll
    for (int r = 0; r < 4; ++r) rs[r] = 0.f;
    #pragma unroll
    for (int n = 0; n < 4; ++n)
      #pragma unroll
      for (int r = 0; r < 4; ++r) {
        const float p = __expf(sf[n][r] - m[r]);
        sf[n][r] = p;
        rs[r] += p;
      }
    #pragma unroll
    for (int r = 0; r < 4; ++r) {
      rs[r] += __shfl_xor(rs[r], 1);
      rs[r] += __shfl_xor(rs[r], 2);
      rs[r] += __shfl_xor(rs[r], 4);
      rs[r] += __shfl_xor(rs[r], 8);
      l[r] = l[r] * corr[r] + rs[r];
    }

    #pragma unroll
    for (int n = 0; n < 4; ++n)
      #pragma unroll
      for (int r = 0; r < 4; ++r)
        p_lds[w][(lg * 4 + r) * 72 + n * 16 + lc] = f2bf(sf[n][r]);

    #pragma unroll
    for (int n = 0; n < 4; ++n)
      #pragma unroll
      for (int r = 0; r < 4; ++r)
        o[n][r] *= corr[r];

    #pragma unroll
    for (int s = 0; s < 2; ++s) {
      const bf16x8 pa = *(const bf16x8*)&p_lds[w][lc * 72 + s * 32 + lg * 8];
      #pragma unroll
      for (int n = 0; n < 4; ++n) {
        const int h = n * 16 + lc;
        const bf16x8 vf = *(const bf16x8*)((const char*)vt_lds + h * 128 +
                              ((s * 64 + lg * 16) ^ ((h & 7) << 4)));
        o[n] = __builtin_amdgcn_mfma_f32_16x16x32_bf16(pa, vf, o[n], 0, 0, 0);
      }
    }
  }

  #pragma unroll
  for (int r = 0; r < 4; ++r) {
    const float inv = 1.f / l[r];
    const long row = (long)b * SEQ + q0 + w * 16 + lg * 4 + r;
    #pragma unroll
    for (int n = 0; n < 4; ++n)
      out[row * HD + n * 16 + lc] = o[n][r] * inv;
  }
}

extern "C" void kernel_launch(void* const* d_in, const int* in_sizes, int n_in,
                              void* d_out, int out_size, void* d_ws, size_t ws_size,
                              hipStream_t stream) {
  const float* x  = (const float*)d_in[0];
  const unsigned char* pmask = (const unsigned char*)d_in[1];
  const float* Wq = (const float*)d_in[2];
  const float* bq = (const float*)d_in[3];
  const float* Wk = (const float*)d_in[4];
  const float* bk = (const float*)d_in[5];
  const float* Wv = (const float*)d_in[6];
  const float* bv = (const float*)d_in[7];
  float* out = (float*)d_out;

  short* Qb = (short*)d_ws;                       // [B*T*H] bf16
  short* Kb = Qb + (size_t)BATCH * SEQ * HD;      // [B*T*H] bf16
  short* Vt = Kb + (size_t)BATCH * SEQ * HD;      // [B*H*T] bf16 (transposed)
  short* Wt = Vt + (size_t)BATCH * SEQ * HD;      // [192*512] bf16 (transposed)

  prep_w<<<dim3(24), dim3(256), 0, stream>>>(Wq, Wk, Wv, Wt);
  qkv_gemm<<<dim3((BATCH * SEQ) / 64), dim3(256), 0, stream>>>(
      x, Wt, bq, bk, bv, Qb, Kb, Vt);
  attn_kernel<<<dim3(SEQ / 64, BATCH), dim3(256), 0, stream>>>(
      Qb, Kb, Vt, pmask, out);
}

// Round 3
// 64.565 us; speedup vs baseline: 2.2482x; 1.3908x over previous
//
#include <hip/hip_runtime.h>
#include <hip/hip_bf16.h>

#define BATCH 8
#define SEQ   2048
#define DIM   512
#define HD    64
#define NEGV  (-1e30f)
#define ROWS  (BATCH * SEQ)   // 16384

typedef float f32x4  __attribute__((ext_vector_type(4)));
typedef short bf16x8 __attribute__((ext_vector_type(8)));
typedef short bf16x4 __attribute__((ext_vector_type(4)));

__device__ __forceinline__ short f2bf(float f) {
  unsigned u = __builtin_bit_cast(unsigned, f);
  u += 0x7fffu + ((u >> 16) & 1u);
  return (short)(u >> 16);
}

// ---------------- Kernel 0: W transpose+convert -> Wt bf16 [192][512] -------
__global__ __launch_bounds__(256) void prep_w(
    const float* __restrict__ Wq, const float* __restrict__ Wk,
    const float* __restrict__ Wv, short* __restrict__ Wt)
{
  __shared__ float lds[64][65];
  const int mat = blockIdx.x % 3;
  const int kb  = blockIdx.x / 3;
  const float* W = mat == 0 ? Wq : (mat == 1 ? Wk : Wv);
  const int tid = threadIdx.x;

  #pragma unroll
  for (int i = 0; i < 4; ++i) {
    const int kr = i * 16 + (tid >> 4);
    const int col = (tid & 15) * 4;
    *(float4*)&lds[kr][col] = *(const float4*)&W[(kb * 64 + kr) * HD + col];
  }
  __syncthreads();
  #pragma unroll
  for (int i = 0; i < 2; ++i) {
    const int c = tid + i * 256;
    const int n = c >> 3, seg = c & 7;
    bf16x8 o;
    #pragma unroll
    for (int j = 0; j < 8; ++j) o[j] = f2bf(lds[seg * 8 + j][n]);
    *(bf16x8*)&Wt[(mat * 64 + n) * DIM + kb * 64 + seg * 8] = o;
  }
}

// ---------------- Kernel 1: QKV projection via MFMA --------------------------
__global__ __launch_bounds__(256) void qkv_gemm(
    const float* __restrict__ x, const short* __restrict__ Wt,
    const float* __restrict__ bq, const float* __restrict__ bk,
    const float* __restrict__ bv,
    short* __restrict__ Qb, short* __restrict__ Kb, short* __restrict__ Vt)
{
  __shared__ short xs[64 * 40];
  __shared__ short ws[192 * 40];

  const int tid  = threadIdx.x;
  const int lane = tid & 63;
  const int w    = tid >> 6;
  const int lc   = lane & 15;
  const int lg   = lane >> 4;
  const long r0  = (long)blockIdx.x * 64;

  f32x4 acc[4][3];
  #pragma unroll
  for (int m = 0; m < 4; ++m)
    #pragma unroll
    for (int n = 0; n < 3; ++n)
      #pragma unroll
      for (int i = 0; i < 4; ++i) acc[m][n][i] = 0.f;

  float4 xv[2];
  bf16x8 wv[3];

  auto load_tile = [&](int k0) {
    #pragma unroll
    for (int i = 0; i < 2; ++i) {
      const int c = tid + i * 256, row = c >> 3, seg = c & 7;
      xv[i] = *(const float4*)&x[(r0 + row) * DIM + k0 + seg * 4];
    }
    #pragma unroll
    for (int i = 0; i < 3; ++i) {
      const int c = tid + i * 256, row = c >> 2, seg = c & 3;
      wv[i] = *(const bf16x8*)&Wt[row * DIM + k0 + seg * 8];
    }
  };
  auto write_tile = [&]() {
    #pragma unroll
    for (int i = 0; i < 2; ++i) {
      const int c = tid + i * 256, row = c >> 3, seg = c & 7;
      bf16x4 t;
      t[0] = f2bf(xv[i].x); t[1] = f2bf(xv[i].y);
      t[2] = f2bf(xv[i].z); t[3] = f2bf(xv[i].w);
      *(bf16x4*)&xs[row * 40 + seg * 4] = t;
    }
    #pragma unroll
    for (int i = 0; i < 3; ++i) {
      const int c = tid + i * 256, row = c >> 2, seg = c & 3;
      *(bf16x8*)&ws[row * 40 + seg * 8] = wv[i];
    }
  };

  load_tile(0);
  write_tile();
  __syncthreads();

  for (int kt = 0; kt < 16; ++kt) {
    if (kt < 15) load_tile((kt + 1) * 32);

    bf16x8 a[4], b[3];
    #pragma unroll
    for (int m = 0; m < 4; ++m)
      a[m] = *(const bf16x8*)&xs[(m * 16 + lc) * 40 + lg * 8];
    #pragma unroll
    for (int n = 0; n < 3; ++n)
      b[n] = *(const bf16x8*)&ws[(w * 48 + n * 16 + lc) * 40 + lg * 8];
    #pragma unroll
    for (int m = 0; m < 4; ++m)
      #pragma unroll
      for (int n = 0; n < 3; ++n)
        acc[m][n] = __builtin_amdgcn_mfma_f32_16x16x32_bf16(a[m], b[n], acc[m][n], 0, 0, 0);

    __syncthreads();
    if (kt < 15) {
      write_tile();
      __syncthreads();
    }
  }

  #pragma unroll
  for (int n = 0; n < 3; ++n) {
    const int col = w * 48 + n * 16 + lc;
    const int mat = col >> 6;
    const int h   = col & 63;
    const float bias = (mat == 0 ? bq : (mat == 1 ? bk : bv))[h];
    #pragma unroll
    for (int m = 0; m < 4; ++m)
      #pragma unroll
      for (int r = 0; r < 4; ++r) {
        const long row = r0 + m * 16 + lg * 4 + r;
        const short o = f2bf(acc[m][n][r] + bias);
        if (mat == 0)      Qb[row * HD + h] = o;
        else if (mat == 1) Kb[row * HD + h] = o;
        else {
          const int bb = (int)(row >> 11), t = (int)(row & 2047);
          Vt[((long)bb * HD + h) * SEQ + t] = o;
        }
      }
  }
}

// ---------------- Kernel 2: flash attention, split-K + prefetch -------------
// Grid 512: bid<256 -> (b=bid>>5, qt=bid&31, half=0); else (b, qt=31-s, half=1).
// Complementary costs land on the same CU under round-robin dispatch.
template<bool SPLIT>
__global__ __launch_bounds__(256) void attn_kernel(
    const short* __restrict__ Qb, const short* __restrict__ Kb,
    const short* __restrict__ Vt, const unsigned char* __restrict__ pmask,
    float* __restrict__ out, float* __restrict__ Opart, float* __restrict__ ml)
{
  __shared__ short kt_lds[64 * 64];   // [key][h], XOR-swizzled rows (128B)
  __shared__ short vt_lds[64 * 64];   // [h][key], XOR-swizzled rows (128B)
  __shared__ float mask_lds[64];
  __shared__ short p_lds[4][16 * 72];

  const int bid = blockIdx.x;
  int b, qt, half;
  if (bid < 256) { b = bid >> 5; qt = bid & 31; half = 0; }
  else { const int t = bid - 256; b = t >> 5; qt = 31 - (t & 31); half = 1; }

  const int nkt      = qt + 1;
  const int hsplit   = SPLIT ? ((nkt + 1) >> 1) : nkt;
  const int kt_begin = half ? hsplit : 0;
  const int kt_end   = half ? nkt : hsplit;
  const int q0       = qt * 64;
  const int tid      = threadIdx.x;

  if (kt_begin >= kt_end) {
    if (SPLIT) {   // empty half-1 task: write zero partial
      #pragma unroll
      for (int i = 0; i < 4; ++i) {
        const int idx = tid + i * 256;
        const int rr = idx >> 4, c4 = (idx & 15) << 2;
        const long row = (long)b * SEQ + q0 + rr;
        f32x4 z; z[0] = 0.f; z[1] = 0.f; z[2] = 0.f; z[3] = 0.f;
        *(f32x4*)&Opart[(ROWS + row) * HD + c4] = z;
      }
      if (tid < 64) {
        const long row = (long)b * SEQ + q0 + tid;
        ml[(ROWS + row) * 2 + 0] = NEGV;
        ml[(ROWS + row) * 2 + 1] = 0.f;
      }
    }
    return;
  }

  const int w    = tid >> 6;
  const int lane = tid & 63;
  const int lc   = lane & 15;
  const int lg   = lane >> 4;

  const long qrow = (long)b * SEQ + q0 + w * 16 + lc;
  bf16x8 qf[2];
  #pragma unroll
  for (int s = 0; s < 2; ++s)
    qf[s] = *(const bf16x8*)&Qb[qrow * HD + s * 32 + lg * 8];

  f32x4 o[4];
  #pragma unroll
  for (int n = 0; n < 4; ++n)
    #pragma unroll
    for (int i = 0; i < 4; ++i) o[n][i] = 0.f;
  float m[4], l[4];
  #pragma unroll
  for (int r = 0; r < 4; ++r) { m[r] = NEGV; l[r] = 0.f; }

  bf16x8 kreg[2], vreg[2];
  float mreg = 0.f;

  auto load_regs = [&](int kt) {
    #pragma unroll
    for (int i = 0; i < 2; ++i) {
      const int idx = tid + i * 256;
      const int row = idx >> 3, seg = idx & 7;
      kreg[i] = *(const bf16x8*)&Kb[((long)b * SEQ + kt * 64 + row) * HD + seg * 8];
      vreg[i] = *(const bf16x8*)&Vt[((long)b * HD + row) * SEQ + kt * 64 + seg * 8];
    }
    if (tid < 64)
      mreg = pmask[(long)b * SEQ + kt * 64 + tid] ? NEGV : 0.f;
  };
  auto write_lds = [&]() {
    #pragma unroll
    for (int i = 0; i < 2; ++i) {
      const int idx = tid + i * 256;
      const int row = idx >> 3, cb = (idx & 7) << 4;
      const int swz = cb ^ ((row & 7) << 4);
      *(bf16x8*)((char*)kt_lds + row * 128 + swz) = kreg[i];
      *(bf16x8*)((char*)vt_lds + row * 128 + swz) = vreg[i];
    }
    if (tid < 64) mask_lds[tid] = mreg;
  };

  load_regs(kt_begin);
  write_lds();
  __syncthreads();

  for (int kt = kt_begin; kt < kt_end; ++kt) {
    const bool more = (kt + 1 < kt_end);
    if (more) load_regs(kt + 1);   // prefetch: global->reg overlaps compute

    f32x4 sf[4];
    #pragma unroll
    for (int n = 0; n < 4; ++n) {
      f32x4 acc;
      #pragma unroll
      for (int i = 0; i < 4; ++i) acc[i] = 0.f;
      const int row = n * 16 + lc;
      #pragma unroll
      for (int s = 0; s < 2; ++s) {
        bf16x8 kf = *(const bf16x8*)((const char*)kt_lds + row * 128 +
                        ((s * 64 + lg * 16) ^ ((row & 7) << 4)));
        acc = __builtin_amdgcn_mfma_f32_16x16x32_bf16(qf[s], kf, acc, 0, 0, 0);
      }
      sf[n] = acc;
    }

    const bool diag = (kt == qt);
    #pragma unroll
    for (int n = 0; n < 4; ++n) {
      const int key = kt * 64 + n * 16 + lc;
      const float madd = mask_lds[n * 16 + lc];
      #pragma unroll
      for (int r = 0; r < 4; ++r) {
        float v = sf[n][r] * 0.125f + madd;
        if (diag) {
          const int q = q0 + w * 16 + lg * 4 + r;
          if (key > q) v = NEGV;
        }
        sf[n][r] = v;
      }
    }

    float tm[4];
    #pragma unroll
    for (int r = 0; r < 4; ++r)
      tm[r] = fmaxf(fmaxf(sf[0][r], sf[1][r]), fmaxf(sf[2][r], sf[3][r]));
    #pragma unroll
    for (int r = 0; r < 4; ++r) {
      tm[r] = fmaxf(tm[r], __shfl_xor(tm[r], 1));
      tm[r] = fmaxf(tm[r], __shfl_xor(tm[r], 2));
      tm[r] = fmaxf(tm[r], __shfl_xor(tm[r], 4));
      tm[r] = fmaxf(tm[r], __shfl_xor(tm[r], 8));
    }
    float corr[4];
    #pragma unroll
    for (int r = 0; r < 4; ++r) {
      const float mn = fmaxf(m[r], tm[r]);
      corr[r] = __expf(m[r] - mn);
      m[r] = mn;
    }
    float rs[4];
    #pragma unroll
    for (int r = 0; r < 4; ++r) rs[r] = 0.f;
    #pragma unroll
    for (int n = 0; n < 4; ++n)
      #pragma unroll
      for (int r = 0; r < 4; ++r) {
        const float p = __expf(sf[n][r] - m[r]);
        sf[n][r] = p;
        rs[r] += p;
      }
    #pragma unroll
    for (int r = 0; r < 4; ++r) {
      rs[r] += __shfl_xor(rs[r], 1);
      rs[r] += __shfl_xor(rs[r], 2);
      rs[r] += __shfl_xor(rs[r], 4);
      rs[r] += __shfl_xor(rs[r], 8);
      l[r] = l[r] * corr[r] + rs[r];
    }

    #pragma unroll
    for (int n = 0; n < 4; ++n)
      #pragma unroll
      for (int r = 0; r < 4; ++r)
        p_lds[w][(lg * 4 + r) * 72 + n * 16 + lc] = f2bf(sf[n][r]);

    #pragma unroll
    for (int n = 0; n < 4; ++n)
      #pragma unroll
      for (int r = 0; r < 4; ++r)
        o[n][r] *= corr[r];

    #pragma unroll
    for (int s = 0; s < 2; ++s) {
      const bf16x8 pa = *(const bf16x8*)&p_lds[w][lc * 72 + s * 32 + lg * 8];
      #pragma unroll
      for (int n = 0; n < 4; ++n) {
        const int h = n * 16 + lc;
        const bf16x8 vf = *(const bf16x8*)((const char*)vt_lds + h * 128 +
                              ((s * 64 + lg * 16) ^ ((h & 7) << 4)));
        o[n] = __builtin_amdgcn_mfma_f32_16x16x32_bf16(pa, vf, o[n], 0, 0, 0);
      }
    }

    __syncthreads();
    if (more) {
      write_lds();
      __syncthreads();
    }
  }

  if (SPLIT) {
    #pragma unroll
    for (int r = 0; r < 4; ++r) {
      const long row = (long)b * SEQ + q0 + w * 16 + lg * 4 + r;
      const long prow = (long)half * ROWS + row;
      #pragma unroll
      for (int n = 0; n < 4; ++n)
        Opart[prow * HD + n * 16 + lc] = o[n][r];
      if (lc == 0) {
        ml[prow * 2 + 0] = m[r];
        ml[prow * 2 + 1] = l[r];
      }
    }
  } else {
    #pragma unroll
    for (int r = 0; r < 4; ++r) {
      const float inv = 1.f / l[r];
      const long row = (long)b * SEQ + q0 + w * 16 + lg * 4 + r;
      #pragma unroll
      for (int n = 0; n < 4; ++n)
        out[row * HD + n * 16 + lc] = o[n][r] * inv;
    }
  }
}

// ---------------- Kernel 3: merge the two split-K partials ------------------
__global__ __launch_bounds__(256) void combine_kernel(
    const float* __restrict__ Opart, const float* __restrict__ ml,
    float* __restrict__ out)
{
  const int g = blockIdx.x * 256 + threadIdx.x;   // ROWS*16 total
  const int row = g >> 4;
  const int c4  = (g & 15) << 2;
  const float m0 = ml[(long)row * 2 + 0];
  const float l0 = ml[(long)row * 2 + 1];
  const float m1 = ml[((long)ROWS + row) * 2 + 0];
  const float l1 = ml[((long)ROWS + row) * 2 + 1];
  const float M  = fmaxf(m0, m1);
  const float w0 = __expf(m0 - M);
  const float w1 = __expf(m1 - M);
  const float inv = 1.f / (l0 * w0 + l1 * w1);
  const f32x4 o0 = *(const f32x4*)&Opart[(long)row * HD + c4];
  const f32x4 o1 = *(const f32x4*)&Opart[((long)ROWS + row) * HD + c4];
  f32x4 r;
  #pragma unroll
  for (int j = 0; j < 4; ++j)
    r[j] = (o0[j] * w0 + o1[j] * w1) * inv;
  *(f32x4*)&out[(long)row * HD + c4] = r;
}

extern "C" void kernel_launch(void* const* d_in, const int* in_sizes, int n_in,
                              void* d_out, int out_size, void* d_ws, size_t ws_size,
                              hipStream_t stream) {
  const float* x  = (const float*)d_in[0];
  const unsigned char* pmask = (const unsigned char*)d_in[1];
  const float* Wq = (const float*)d_in[2];
  const float* bq = (const float*)d_in[3];
  const float* Wk = (const float*)d_in[4];
  const float* bk = (const float*)d_in[5];
  const float* Wv = (const float*)d_in[6];
  const float* bv = (const float*)d_in[7];
  float* out = (float*)d_out;

  short* Qb = (short*)d_ws;                         // [B*T*H] bf16
  short* Kb = Qb + (size_t)ROWS * HD;               // [B*T*H] bf16
  short* Vt = Kb + (size_t)ROWS * HD;               // [B*H*T] bf16
  short* Wt = Vt + (size_t)ROWS * HD;               // [192*512] bf16
  float* Opart = (float*)(Wt + 192 * DIM);          // [2][ROWS][HD] f32
  float* ml    = Opart + 2ull * ROWS * HD;          // [2][ROWS][2] f32

  const size_t need = ((size_t)3 * ROWS * HD + 192 * DIM) * 2 +
                      (2ull * ROWS * HD + 2ull * ROWS * 2) * 4;
  const bool split = ws_size >= need;

  prep_w<<<dim3(24), dim3(256), 0, stream>>>(Wq, Wk, Wv, Wt);
  qkv_gemm<<<dim3(ROWS / 64), dim3(256), 0, stream>>>(
      x, Wt, bq, bk, bv, Qb, Kb, Vt);
  if (split) {
    attn_kernel<true><<<dim3(512), dim3(256), 0, stream>>>(
        Qb, Kb, Vt, pmask, out, Opart, ml);
    combine_kernel<<<dim3(ROWS * 16 / 256), dim3(256), 0, stream>>>(Opart, ml, out);
  } else {
    attn_kernel<false><<<dim3(512), dim3(256), 0, stream>>>(
        Qb, Kb, Vt, pmask, out, Opart, ml);
  }
}